// Round 1
// 302.405 us; speedup vs baseline: 1.0106x; 1.0106x over previous
//
#include <hip/hip_runtime.h>
#include <hip/hip_bf16.h>
#include <cstdint>

typedef __attribute__((ext_vector_type(8))) short bf16x8;   // 8 bf16 (4 VGPRs)
typedef __attribute__((ext_vector_type(4))) float f32x4;    // MFMA C/D

#define BN_EPS 1e-5f

// ---------------------------------------------------------------------------
// prep1: fold BN1 + ring telescoping into V (box-feature weights), b1eff.
// ---------------------------------------------------------------------------
__global__ __launch_bounds__(256) void prep1_kernel(
    const float* __restrict__ W1, const float* __restrict__ cb1,
    const float* __restrict__ g1, const float* __restrict__ be1,
    const float* __restrict__ mu1, const float* __restrict__ va1,
    __hip_bfloat16* __restrict__ V, float* __restrict__ b1e)
{
  int o = blockIdx.x;
  int t = threadIdx.x;
  const float* wrow = W1 + (size_t)o * 1248;
  float acc = 0.f;
  for (int i = t; i < 1248; i += 256) {
    float s = g1[i] * rsqrtf(va1[i] + BN_EPS);
    float w = wrow[i];
    acc += w * (be1[i] - mu1[i] * s);
    float g = w * s;
    float gn = 0.f;
    if (i < 1152) {  // has a next-ring partner
      float sn = g1[i + 96] * rsqrtf(va1[i + 96] + BN_EPS);
      gn = wrow[i + 96] * sn;
    }
    V[(size_t)o * 1248 + i] = __float2bfloat16(g - gn);
  }
  for (int d = 32; d > 0; d >>= 1) acc += __shfl_down(acc, d);
  __shared__ float red[4];
  int lane = t & 63, wv = t >> 6;
  if (lane == 0) red[wv] = acc;
  __syncthreads();
  if (t == 0) b1e[o] = cb1[o] + red[0] + red[1] + red[2] + red[3];
}

// ---------------------------------------------------------------------------
// prep2: fold BN2 into W2eff, b2eff.
// ---------------------------------------------------------------------------
__global__ __launch_bounds__(256) void prep2_kernel(
    const float* __restrict__ W2, const float* __restrict__ cb2,
    const float* __restrict__ g2, const float* __restrict__ be2,
    const float* __restrict__ mu2, const float* __restrict__ va2,
    __hip_bfloat16* __restrict__ W2e, float* __restrict__ b2e)
{
  int o = blockIdx.x;
  int t = threadIdx.x;
  const float* wrow = W2 + (size_t)o * 512;
  float acc = 0.f;
  for (int j = t; j < 512; j += 256) {
    float s = g2[j] * rsqrtf(va2[j] + BN_EPS);
    float wv = wrow[j];
    acc += wv * (be2[j] - mu2[j] * s);
    W2e[(size_t)o * 512 + j] = __float2bfloat16(wv * s);
  }
  for (int d = 32; d > 0; d >>= 1) acc += __shfl_down(acc, d);
  __shared__ float red[4];
  int lane = t & 63, wv2 = t >> 6;
  if (lane == 0) red[wv2] = acc;
  __syncthreads();
  if (t == 0) b2e[o] = cb2[o] + red[0] + red[1] + red[2] + red[3];
}

// ---------------------------------------------------------------------------
// sat v3: one block per (b,c) plane, 512 threads (8 waves).
// Row scan:   4 chunks of 8 float4-granules per row (serial depth 8+8 vs 32).
// Column scan: 4 chunks of 32 rows, running values kept in registers
// (serial depth 32 vs 128), cross-chunk prefix via small LDS arrays.
// Exclusive SAT [129][132] layout unchanged.
// ---------------------------------------------------------------------------
__global__ __launch_bounds__(512) void sat_kernel(
    const float* __restrict__ x, float* __restrict__ SAT)
{
  int plane = blockIdx.x;
  const float* xp = x + (size_t)plane * 16384;
  __shared__ float tile[16384];   // [r][granule-swizzled]
  __shared__ float csA[128 * 4];
  __shared__ float csB[128 * 4];
  int t = threadIdx.x;

  // load 4096 granules, swizzled so row-direction access is conflict-free
  for (int i4 = t; i4 < 4096; i4 += 512) {
    int r = i4 >> 5;
    int g = i4 & 31;
    float4 v = *(const float4*)(xp + (size_t)r * 128 + g * 4);
    *(float4*)(tile + r * 128 + ((g ^ (r & 31)) << 2)) = v;
  }
  __syncthreads();

  int r = t & 127, ch = t >> 7;    // thread = (row, granule-chunk of 8)
  {  // phase A1: chunk-local row prefix
    float carry = 0.f;
#pragma unroll
    for (int g8 = 0; g8 < 8; ++g8) {
      int g = ch * 8 + g8;
      float* p = tile + r * 128 + ((g ^ (r & 31)) << 2);
      float4 v = *(float4*)p;
      float s0 = carry + v.x, s1 = s0 + v.y, s2 = s1 + v.z, s3 = s2 + v.w;
      float4 o; o.x = s0; o.y = s1; o.z = s2; o.w = s3;
      *(float4*)p = o;
      carry = s3;
    }
    csA[r * 4 + ch] = carry;
  }
  __syncthreads();
  if (ch > 0) {  // phase A2: add prefix of previous chunks
    float offs = csA[r * 4 + 0];
    if (ch > 1) offs += csA[r * 4 + 1];
    if (ch > 2) offs += csA[r * 4 + 2];
#pragma unroll
    for (int g8 = 0; g8 < 8; ++g8) {
      int g = ch * 8 + g8;
      float* p = tile + r * 128 + ((g ^ (r & 31)) << 2);
      float4 v = *(float4*)p;
      v.x += offs; v.y += offs; v.z += offs; v.w += offs;
      *(float4*)p = v;
    }
  }
  __syncthreads();

  // phase B1: column partial sums, thread = (column, row-chunk of 32)
  float* Sg = SAT + (size_t)plane * 17028;  // 129*132
  int xcol = t & 127, rc = t >> 7;
  int gc = xcol >> 2, wc = xcol & 3;
  float regs[32];
  {
    float run = 0.f;
#pragma unroll
    for (int r8 = 0; r8 < 32; ++r8) {
      int rr = rc * 32 + r8;
      run += tile[rr * 128 + ((gc ^ (rr & 31)) << 2) + wc];
      regs[r8] = run;
    }
    csB[xcol * 4 + rc] = run;
  }
  // zero fills (disjoint from phase-B2 writes)
  if (t < 132) Sg[t] = 0.f;                 // row 0, cols 0..131
  if (t < 128) Sg[(t + 1) * 132] = 0.f;     // col 0, rows 1..128
  __syncthreads();

  float offs = 0.f;
  if (rc > 0) offs += csB[xcol * 4 + 0];
  if (rc > 1) offs += csB[xcol * 4 + 1];
  if (rc > 2) offs += csB[xcol * 4 + 2];
#pragma unroll
  for (int r8 = 0; r8 < 32; ++r8) {
    int rr = rc * 32 + r8;
    Sg[(rr + 1) * 132 + xcol + 1] = regs[r8] + offs;
  }
}

// ---------------------------------------------------------------------------
// fused v5: single barrier per ring. Double-buffered E AND As:
//   iter j: { build As[(j+1)&1] <- E[(j+1)&1] ; efill E[j&1] <- ring j+2 ;
//             MFMA(j) <- As[j&1] } ; one __syncthreads().
// Wave-parity role split (odd waves MFMA-first, even waves efill/build-first)
// keeps the matrix and DS pipes simultaneously fed from phase start.
// LDS: E0,E1 (50688 each) + As0,As1 (26624 each) = 154624 B; epilogue Yst
// (133120 B) reuses the same region. Build/efill/MFMA bodies identical to v4.
// ---------------------------------------------------------------------------
__global__ __launch_bounds__(1024) void fused1_kernel(
    const float* __restrict__ SAT, const __hip_bfloat16* __restrict__ V,
    const float* __restrict__ b1e, const __hip_bfloat16* __restrict__ W2e,
    const float* __restrict__ b2e, float* __restrict__ out, int nb, int b0)
{
  extern __shared__ __align__(16) char smem[];
  float* E0 = (float*)smem;                                  // 96*132 fp32
  float* E1 = (float*)(smem + 50688);
  __hip_bfloat16* As0 = (__hip_bfloat16*)(smem + 101376);    // [128][104]
  __hip_bfloat16* As1 = (__hip_bfloat16*)(smem + 128000);

  int blk = blockIdx.x;
  int rows_per_xcd = (nb * 128) >> 3;
  int r = (blk & 7) * rows_per_xcd + (blk >> 3);
  int bL = r >> 7, y = r & 127;

  int t = threadIdx.x;
  int lane = t & 63, wv = t >> 6;              // 16 waves
  int wm = wv & 1, wn = wv >> 1;               // M-half (64), N-slab (64)
  int lr = lane & 15, quad = lane >> 4;
  int px = t & 127;                            // build pixel
  int bg = t >> 7;                             // build granule 0..7

  const float* Sb = SAT + (size_t)bL * 96 * 17028;

  f32x4 acc[4][4];
#pragma unroll
  for (int i = 0; i < 4; ++i)
#pragma unroll
    for (int jn = 0; jn < 4; ++jn) acc[i][jn] = (f32x4){0.f, 0.f, 0.f, 0.f};

  // E-fill for ring jr into buffer E: 96 ch x 33 float4 granules
  auto efill = [&](float* E, int jr) {
    int y1 = (y - jr < 0) ? 0 : (y - jr);
    int y2 = ((y + jr > 127) ? 127 : (y + jr)) + 1;
    for (int idx = t; idx < 3168; idx += 1024) {
      int cl = idx / 33;
      int ck = idx - cl * 33;
      const float* bp = Sb + (size_t)cl * 17028 + ck * 4;
      float4 a = *(const float4*)(bp + y2 * 132);
      float4 b = *(const float4*)(bp + y1 * 132);
      float4 d;
      d.x = a.x - b.x; d.y = a.y - b.y; d.z = a.z - b.z; d.w = a.w - b.w;
      *(float4*)(E + cl * 132 + ck * 4) = d;
    }
  };

  // build As tile for ring jr from E buffer
  auto build = [&](__hip_bfloat16* As, const float* E, int jr) {
    int x1 = (px - jr < 0) ? 0 : (px - jr);
    int x2 = ((px + jr > 127) ? 127 : (px + jr)) + 1;
    const float* Eb = E + bg * 8 * 132;
    union { bf16x8 v; __hip_bfloat16 h[8]; } pk;
#pragma unroll
    for (int i = 0; i < 8; ++i)
      pk.h[i] = __float2bfloat16(Eb[i * 132 + x2] - Eb[i * 132 + x1]);
    *(bf16x8*)(As + px * 104 + bg * 8) = pk.v;
    if (bg < 4) {
      const float* Eb2 = E + (8 + bg) * 8 * 132;
      union { bf16x8 v; __hip_bfloat16 h[8]; } pk2;
#pragma unroll
      for (int i = 0; i < 8; ++i)
        pk2.h[i] = __float2bfloat16(Eb2[i * 132 + x2] - Eb2[i * 132 + x1]);
      *(bf16x8*)(As + px * 104 + (8 + bg) * 8) = pk2.v;
    }
  };

  // 48 MFMAs for ring j from As buffer
  auto mfma_ring = [&](int j, const __hip_bfloat16* As) {
    __builtin_amdgcn_s_setprio(1);
#pragma unroll
    for (int sub = 0; sub < 3; ++sub) {
      bf16x8 af[4], bfr[4];
#pragma unroll
      for (int i = 0; i < 4; ++i)
        af[i] = *(const bf16x8*)(As + (wm * 64 + i * 16 + lr) * 104 + sub * 32 + quad * 8);
#pragma unroll
      for (int jn = 0; jn < 4; ++jn)
        bfr[jn] = *(const bf16x8*)(V + (size_t)(wn * 64 + jn * 16 + lr) * 1248
                                   + j * 96 + sub * 32 + quad * 8);
#pragma unroll
      for (int i = 0; i < 4; ++i)
#pragma unroll
        for (int jn = 0; jn < 4; ++jn)
          acc[i][jn] = __builtin_amdgcn_mfma_f32_16x16x32_bf16(af[i], bfr[jn], acc[i][jn], 0, 0, 0);
    }
    __builtin_amdgcn_s_setprio(0);
  };

  // one ring iteration: single barrier, parity-split wave roles
  auto ring_iter = [&](int j, const float* Esrc, float* Edst,
                       const __hip_bfloat16* Asrc, __hip_bfloat16* Adst) {
    if (wv & 1) {
      mfma_ring(j, Asrc);
      if (j < 11) efill(Edst, j + 2);
      if (j < 12) build(Adst, Esrc, j + 1);
    } else {
      if (j < 11) efill(Edst, j + 2);
      if (j < 12) build(Adst, Esrc, j + 1);
      mfma_ring(j, Asrc);
    }
    __syncthreads();
  };

  // prologue: E0 <- ring0; As0 <- ring0; E1 <- ring1
  efill(E0, 0);
  __syncthreads();
  efill(E1, 1);
  build(As0, E0, 0);
  __syncthreads();

  for (int j = 0; j < 13; j += 2) {
    ring_iter(j, E1, E0, As0, As1);
    if (j + 1 < 13) ring_iter(j + 1, E0, E1, As1, As0);
  }

  // ---- epilogue A: bias+relu -> Yst[128][520] bf16 (row stride 260 words
  //      == 4 mod 32 -> conflict-free b128 reads below) ----
  __hip_bfloat16* Yst = (__hip_bfloat16*)smem;   // 128*520*2 = 133120 B
#pragma unroll
  for (int jn = 0; jn < 4; ++jn) {
    int n = wn * 64 + jn * 16 + lr;
    float bias = b1e[n];
#pragma unroll
    for (int i = 0; i < 4; ++i) {
#pragma unroll
      for (int rr = 0; rr < 4; ++rr) {
        int m = wm * 64 + i * 16 + quad * 4 + rr;
        float z = acc[i][jn][rr] + bias;
        z = z > 0.f ? z : 0.f;
        Yst[m * 520 + n] = __float2bfloat16(z);
      }
    }
  }
  __syncthreads();

  // ---- epilogue B: out[96][128px] = W2e[96][512] x Yst^T. 48 16x16 tiles,
  //      wave = (px-tile, m-half-of-96): 3 tiles each. ----
  int pxt = wv & 7;          // px tile
  int mh = wv >> 3;          // 0: o2 0..47, 1: o2 48..95
  f32x4 acc2[3];
#pragma unroll
  for (int im = 0; im < 3; ++im) acc2[im] = (f32x4){0.f, 0.f, 0.f, 0.f};

  for (int k2 = 0; k2 < 512; k2 += 32) {
    bf16x8 bfr2 = *(const bf16x8*)(Yst + (pxt * 16 + lr) * 520 + k2 + quad * 8);
#pragma unroll
    for (int im = 0; im < 3; ++im) {
      bf16x8 afr2 = *(const bf16x8*)(W2e + (size_t)(mh * 48 + im * 16 + lr) * 512
                                     + k2 + quad * 8);
      acc2[im] = __builtin_amdgcn_mfma_f32_16x16x32_bf16(afr2, bfr2, acc2[im], 0, 0, 0);
    }
  }

  size_t obase = ((size_t)(b0 + bL) * 96) * 16384 + (size_t)y * 128 + pxt * 16 + lr;
#pragma unroll
  for (int im = 0; im < 3; ++im) {
#pragma unroll
    for (int rr = 0; rr < 4; ++rr) {
      int o2 = mh * 48 + im * 16 + quad * 4 + rr;
      out[obase + (size_t)o2 * 16384] = acc2[im][rr] + b2e[o2];
    }
  }
}

// ---------------------------------------------------------------------------
extern "C" void kernel_launch(void* const* d_in, const int* in_sizes, int n_in,
                              void* d_out, int out_size, void* d_ws, size_t ws_size,
                              hipStream_t stream)
{
  const float* x   = (const float*)d_in[0];
  const float* g1  = (const float*)d_in[1];
  const float* be1 = (const float*)d_in[2];
  const float* mu1 = (const float*)d_in[3];
  const float* va1 = (const float*)d_in[4];
  const float* W1  = (const float*)d_in[5];
  const float* cb1 = (const float*)d_in[6];
  const float* g2  = (const float*)d_in[7];
  const float* be2 = (const float*)d_in[8];
  const float* mu2 = (const float*)d_in[9];
  const float* va2 = (const float*)d_in[10];
  const float* W2  = (const float*)d_in[11];
  const float* cb2 = (const float*)d_in[12];
  float* out = (float*)d_out;

  hipFuncSetAttribute((const void*)fused1_kernel,
                      hipFuncAttributeMaxDynamicSharedMemorySize, 154624);

  char* w = (char*)d_ws;
  __hip_bfloat16* V   = (__hip_bfloat16*)w; w += (size_t)512 * 1248 * 2;
  __hip_bfloat16* W2e = (__hip_bfloat16*)w; w += (size_t)96 * 512 * 2;
  float* b1e = (float*)w; w += 2048;
  float* b2e = (float*)w; w += 512;
  size_t fixed = (size_t)(w - (char*)d_ws);

  const size_t satB = (size_t)96 * 17028 * 4;     // per-batch SAT bytes
  int nb = (ws_size >= fixed + 4 * satB + 4096) ? 4 : 1;

  float* SAT = (float*)w;

  prep1_kernel<<<512, 256, 0, stream>>>(W1, cb1, g1, be1, mu1, va1, V, b1e);
  prep2_kernel<<<96, 256, 0, stream>>>(W2, cb2, g2, be2, mu2, va2, W2e, b2e);

  for (int b0 = 0; b0 < 4; b0 += nb) {
    sat_kernel<<<nb * 96, 512, 0, stream>>>(x + (size_t)b0 * 96 * 16384, SAT);
    fused1_kernel<<<nb * 128, 1024, 154624, stream>>>(SAT, V, b1e, W2e, b2e, out, nb, b0);
  }
}

// Round 2
// 288.884 us; speedup vs baseline: 1.0579x; 1.0468x over previous
//
#include <hip/hip_runtime.h>
#include <hip/hip_bf16.h>
#include <cstdint>

typedef __attribute__((ext_vector_type(8))) short bf16x8;   // 8 bf16 (4 VGPRs)
typedef __attribute__((ext_vector_type(4))) short bf16x4;   // 4 bf16 (8 B)
typedef __attribute__((ext_vector_type(4))) float f32x4;    // MFMA C/D

#define BN_EPS 1e-5f

// ---------------------------------------------------------------------------
// prep1: fold BN1 + ring telescoping into V (box-feature weights), b1eff.
// ---------------------------------------------------------------------------
__global__ __launch_bounds__(256) void prep1_kernel(
    const float* __restrict__ W1, const float* __restrict__ cb1,
    const float* __restrict__ g1, const float* __restrict__ be1,
    const float* __restrict__ mu1, const float* __restrict__ va1,
    __hip_bfloat16* __restrict__ V, float* __restrict__ b1e)
{
  int o = blockIdx.x;
  int t = threadIdx.x;
  const float* wrow = W1 + (size_t)o * 1248;
  float acc = 0.f;
  for (int i = t; i < 1248; i += 256) {
    float s = g1[i] * rsqrtf(va1[i] + BN_EPS);
    float w = wrow[i];
    acc += w * (be1[i] - mu1[i] * s);
    float g = w * s;
    float gn = 0.f;
    if (i < 1152) {  // has a next-ring partner
      float sn = g1[i + 96] * rsqrtf(va1[i + 96] + BN_EPS);
      gn = wrow[i + 96] * sn;
    }
    V[(size_t)o * 1248 + i] = __float2bfloat16(g - gn);
  }
  for (int d = 32; d > 0; d >>= 1) acc += __shfl_down(acc, d);
  __shared__ float red[4];
  int lane = t & 63, wv = t >> 6;
  if (lane == 0) red[wv] = acc;
  __syncthreads();
  if (t == 0) b1e[o] = cb1[o] + red[0] + red[1] + red[2] + red[3];
}

// ---------------------------------------------------------------------------
// prep2: fold BN2 into W2eff, b2eff.
// ---------------------------------------------------------------------------
__global__ __launch_bounds__(256) void prep2_kernel(
    const float* __restrict__ W2, const float* __restrict__ cb2,
    const float* __restrict__ g2, const float* __restrict__ be2,
    const float* __restrict__ mu2, const float* __restrict__ va2,
    __hip_bfloat16* __restrict__ W2e, float* __restrict__ b2e)
{
  int o = blockIdx.x;
  int t = threadIdx.x;
  const float* wrow = W2 + (size_t)o * 512;
  float acc = 0.f;
  for (int j = t; j < 512; j += 256) {
    float s = g2[j] * rsqrtf(va2[j] + BN_EPS);
    float wv = wrow[j];
    acc += wv * (be2[j] - mu2[j] * s);
    W2e[(size_t)o * 512 + j] = __float2bfloat16(wv * s);
  }
  for (int d = 32; d > 0; d >>= 1) acc += __shfl_down(acc, d);
  __shared__ float red[4];
  int lane = t & 63, wv2 = t >> 6;
  if (lane == 0) red[wv2] = acc;
  __syncthreads();
  if (t == 0) b2e[o] = cb2[o] + red[0] + red[1] + red[2] + red[3];
}

// ---------------------------------------------------------------------------
// sat v3: one block per (b,c) plane, 512 threads (8 waves). (unchanged)
// ---------------------------------------------------------------------------
__global__ __launch_bounds__(512) void sat_kernel(
    const float* __restrict__ x, float* __restrict__ SAT)
{
  int plane = blockIdx.x;
  const float* xp = x + (size_t)plane * 16384;
  __shared__ float tile[16384];   // [r][granule-swizzled]
  __shared__ float csA[128 * 4];
  __shared__ float csB[128 * 4];
  int t = threadIdx.x;

  for (int i4 = t; i4 < 4096; i4 += 512) {
    int r = i4 >> 5;
    int g = i4 & 31;
    float4 v = *(const float4*)(xp + (size_t)r * 128 + g * 4);
    *(float4*)(tile + r * 128 + ((g ^ (r & 31)) << 2)) = v;
  }
  __syncthreads();

  int r = t & 127, ch = t >> 7;    // thread = (row, granule-chunk of 8)
  {
    float carry = 0.f;
#pragma unroll
    for (int g8 = 0; g8 < 8; ++g8) {
      int g = ch * 8 + g8;
      float* p = tile + r * 128 + ((g ^ (r & 31)) << 2);
      float4 v = *(float4*)p;
      float s0 = carry + v.x, s1 = s0 + v.y, s2 = s1 + v.z, s3 = s2 + v.w;
      float4 o; o.x = s0; o.y = s1; o.z = s2; o.w = s3;
      *(float4*)p = o;
      carry = s3;
    }
    csA[r * 4 + ch] = carry;
  }
  __syncthreads();
  if (ch > 0) {
    float offs = csA[r * 4 + 0];
    if (ch > 1) offs += csA[r * 4 + 1];
    if (ch > 2) offs += csA[r * 4 + 2];
#pragma unroll
    for (int g8 = 0; g8 < 8; ++g8) {
      int g = ch * 8 + g8;
      float* p = tile + r * 128 + ((g ^ (r & 31)) << 2);
      float4 v = *(float4*)p;
      v.x += offs; v.y += offs; v.z += offs; v.w += offs;
      *(float4*)p = v;
    }
  }
  __syncthreads();

  float* Sg = SAT + (size_t)plane * 17028;  // 129*132
  int xcol = t & 127, rc = t >> 7;
  int gc = xcol >> 2, wc = xcol & 3;
  float regs[32];
  {
    float run = 0.f;
#pragma unroll
    for (int r8 = 0; r8 < 32; ++r8) {
      int rr = rc * 32 + r8;
      run += tile[rr * 128 + ((gc ^ (rr & 31)) << 2) + wc];
      regs[r8] = run;
    }
    csB[xcol * 4 + rc] = run;
  }
  if (t < 132) Sg[t] = 0.f;                 // row 0
  if (t < 128) Sg[(t + 1) * 132] = 0.f;     // col 0
  __syncthreads();

  float offs = 0.f;
  if (rc > 0) offs += csB[xcol * 4 + 0];
  if (rc > 1) offs += csB[xcol * 4 + 1];
  if (rc > 2) offs += csB[xcol * 4 + 2];
#pragma unroll
  for (int r8 = 0; r8 < 32; ++r8) {
    int rr = rc * 32 + r8;
    Sg[(rr + 1) * 132 + xcol + 1] = regs[r8] + offs;
  }
}

// ---------------------------------------------------------------------------
// fused v6: 512 threads / 8 waves / 256 regs-per-wave (__launch_bounds(512,2)).
// Rationale: v4/v5 at 1024 thr were capped at 128 regs/wave with a 64-reg
// accumulator -> register starvation -> all pipes <35%, stall-bound.
// Wave tile: M(o1)=128 x N(px)=64, acc[8][4] f32x4 = 128 regs/thread.
// gemm1 operands SWAPPED (A=V, B=As): C-frag rows = o1 -> epilogue-A writes
// 4 consecutive o1 per thread as one b64 (vs 128 scalar b16).
// Per ring: phase A { eload(j+2,h0); mfma sub0; ewrite h0; eload h1;
//                    mfma sub1,2; ewrite h1 }  (T14 async-stage)
//           barrier; phase B { build(As, j+1) }; barrier.
// LDS: E0,E1 (96x132 f32 = 50688 each) + As (128x104 bf16 = 26624) = 128000;
// epilogue Yst[128][520] bf16 = 133120 aliases everything.
// ---------------------------------------------------------------------------
__global__ __launch_bounds__(512, 2) void fused1_kernel(
    const float* __restrict__ SAT, const __hip_bfloat16* __restrict__ V,
    const float* __restrict__ b1e, const __hip_bfloat16* __restrict__ W2e,
    const float* __restrict__ b2e, float* __restrict__ out, int nb, int b0)
{
  extern __shared__ __align__(16) char smem[];
  float* E0 = (float*)smem;                                  // 96*132 fp32
  float* E1 = (float*)(smem + 50688);
  __hip_bfloat16* As = (__hip_bfloat16*)(smem + 101376);     // [128][104]

  int blk = blockIdx.x;
  int rows_per_xcd = (nb * 128) >> 3;
  int r = (blk & 7) * rows_per_xcd + (blk >> 3);
  int bL = r >> 7, y = r & 127;

  int t = threadIdx.x;
  int lane = t & 63, wv = t >> 6;              // 8 waves
  int wo = wv >> 1, wp = wv & 1;               // o1-slab (128), px-half (64)
  int lr = lane & 15, quad = lane >> 4;
  int px = t & 127;                            // build pixel
  int bg = t >> 7;                             // build granule base 0..3

  const float* Sb = SAT + (size_t)bL * 96 * 17028;

  f32x4 acc[8][4];
#pragma unroll
  for (int io = 0; io < 8; ++io)
#pragma unroll
    for (int ip = 0; ip < 4; ++ip) acc[io][ip] = (f32x4){0.f, 0.f, 0.f, 0.f};

  // ---- efill staging registers (T14 split: load early, write late) ----
  float4 ea[3], eb[3];
  float ta = 0.f, tb = 0.f;

  auto eload = [&](int jr, int h) {
    int y1 = ((y - jr < 0) ? 0 : (y - jr)) * 132;
    int y2 = (((y + jr > 127) ? 127 : (y + jr)) + 1) * 132;
#pragma unroll
    for (int k = 0; k < 3; ++k) {
      int idx = t + 512 * (h * 3 + k);
      int cl = idx >> 5, ck = idx & 31;
      const float* bp = Sb + (size_t)cl * 17028 + ck * 4;
      ea[k] = *(const float4*)(bp + y2);
      eb[k] = *(const float4*)(bp + y1);
    }
    if (h == 1 && t < 96) {   // x = 128 column tail
      const float* bp = Sb + (size_t)t * 17028 + 128;
      ta = bp[y2];
      tb = bp[y1];
    }
  };

  auto ewrite = [&](float* E, int h) {
#pragma unroll
    for (int k = 0; k < 3; ++k) {
      int idx = t + 512 * (h * 3 + k);
      int cl = idx >> 5, ck = idx & 31;
      float4 d;
      d.x = ea[k].x - eb[k].x; d.y = ea[k].y - eb[k].y;
      d.z = ea[k].z - eb[k].z; d.w = ea[k].w - eb[k].w;
      *(float4*)(E + cl * 132 + ck * 4) = d;
    }
    if (h == 1 && t < 96) E[t * 132 + 128] = ta - tb;
  };

  // build As tile for ring jr from E buffer (each thread: granules bg,bg+4,bg+8)
  auto build = [&](const float* E, int jr) {
    int x1 = (px - jr < 0) ? 0 : (px - jr);
    int x2 = ((px + jr > 127) ? 127 : (px + jr)) + 1;
#pragma unroll
    for (int k = 0; k < 3; ++k) {
      int g = bg + 4 * k;
      const float* Eb = E + g * 8 * 132;
      union { bf16x8 v; __hip_bfloat16 h[8]; } pk;
#pragma unroll
      for (int i = 0; i < 8; ++i)
        pk.h[i] = __float2bfloat16(Eb[i * 132 + x2] - Eb[i * 132 + x1]);
      *(bf16x8*)(As + px * 104 + g * 8) = pk.v;
    }
  };

  // one K-sub-phase: 8 V-frags (global) x 4 As-frags (LDS) -> 32 MFMA
  auto mfma_sub = [&](int j, int sub) {
    bf16x8 av[8], bs[4];
#pragma unroll
    for (int io = 0; io < 8; ++io)
      av[io] = *(const bf16x8*)(V + (size_t)(wo * 128 + io * 16 + lr) * 1248
                                + j * 96 + sub * 32 + quad * 8);
#pragma unroll
    for (int ip = 0; ip < 4; ++ip)
      bs[ip] = *(const bf16x8*)(As + (wp * 64 + ip * 16 + lr) * 104 + sub * 32 + quad * 8);
    __builtin_amdgcn_s_setprio(1);
#pragma unroll
    for (int io = 0; io < 8; ++io)
#pragma unroll
      for (int ip = 0; ip < 4; ++ip)
        acc[io][ip] = __builtin_amdgcn_mfma_f32_16x16x32_bf16(av[io], bs[ip], acc[io][ip], 0, 0, 0);
    __builtin_amdgcn_s_setprio(0);
  };

  // ---- prologue: E0 <- ring0; then As <- ring0 while E1 <- ring1 ----
  eload(0, 0); ewrite(E0, 0); eload(0, 1); ewrite(E0, 1);
  __syncthreads();
  eload(1, 0); ewrite(E1, 0); eload(1, 1);
  build(E0, 0);
  ewrite(E1, 1);
  __syncthreads();

  // ---- main ring loop: 2 barriers/ring, loads hidden under MFMA ----
  for (int j = 0; j < 13; ++j) {
    float* EJ = (j & 1) ? E1 : E0;          // efill target (ring j+2)
    const float* EK = (j & 1) ? E0 : E1;    // build source (ring j+1)
    bool pf = (j < 11);
    if (pf) eload(j + 2, 0);
    mfma_sub(j, 0);
    if (pf) { ewrite(EJ, 0); eload(j + 2, 1); }
    mfma_sub(j, 1);
    mfma_sub(j, 2);
    if (pf) ewrite(EJ, 1);
    __syncthreads();
    if (j < 12) build(EK, j + 1);
    __syncthreads();
  }

  // ---- epilogue A: bias+relu -> Yst[128 px][520 o1] bf16, b64 packed writes
  //      (swapped-operand C-frag: 4 consecutive o1 per thread) ----
  __hip_bfloat16* Yst = (__hip_bfloat16*)smem;   // 128*520*2 = 133120 B
#pragma unroll
  for (int io = 0; io < 8; ++io) {
    int o1b = wo * 128 + io * 16 + quad * 4;
    float4 bias = *(const float4*)(b1e + o1b);
#pragma unroll
    for (int ip = 0; ip < 4; ++ip) {
      int pxx = wp * 64 + ip * 16 + lr;
      f32x4 a = acc[io][ip];
      float z0 = a[0] + bias.x; z0 = z0 > 0.f ? z0 : 0.f;
      float z1 = a[1] + bias.y; z1 = z1 > 0.f ? z1 : 0.f;
      float z2 = a[2] + bias.z; z2 = z2 > 0.f ? z2 : 0.f;
      float z3 = a[3] + bias.w; z3 = z3 > 0.f ? z3 : 0.f;
      union { bf16x4 v; __hip_bfloat16 h[4]; } pk;
      pk.h[0] = __float2bfloat16(z0); pk.h[1] = __float2bfloat16(z1);
      pk.h[2] = __float2bfloat16(z2); pk.h[3] = __float2bfloat16(z3);
      *(bf16x4*)(Yst + pxx * 520 + o1b) = pk.v;
    }
  }
  __syncthreads();

  // ---- epilogue B: out[96 o2][128 px] = W2e[96][512] x Yst^T.
  //      wave = (o2-group of 48, px-group of 32): 3x2 tiles each. ----
  int og = wv >> 2;          // 0,1
  int pg = wv & 3;           // 0..3
  f32x4 acc2[3][2];
#pragma unroll
  for (int im = 0; im < 3; ++im)
#pragma unroll
    for (int tl = 0; tl < 2; ++tl) acc2[im][tl] = (f32x4){0.f, 0.f, 0.f, 0.f};

  for (int k2 = 0; k2 < 512; k2 += 32) {
    bf16x8 bfr2[2];
#pragma unroll
    for (int tl = 0; tl < 2; ++tl)
      bfr2[tl] = *(const bf16x8*)(Yst + (pg * 32 + tl * 16 + lr) * 520 + k2 + quad * 8);
#pragma unroll
    for (int im = 0; im < 3; ++im) {
      bf16x8 afr2 = *(const bf16x8*)(W2e + (size_t)(og * 48 + im * 16 + lr) * 512
                                     + k2 + quad * 8);
#pragma unroll
      for (int tl = 0; tl < 2; ++tl)
        acc2[im][tl] = __builtin_amdgcn_mfma_f32_16x16x32_bf16(afr2, bfr2[tl], acc2[im][tl], 0, 0, 0);
    }
  }

  size_t obase = ((size_t)(b0 + bL) * 96) * 16384 + (size_t)y * 128;
#pragma unroll
  for (int im = 0; im < 3; ++im) {
#pragma unroll
    for (int tl = 0; tl < 2; ++tl) {
      int pxx = pg * 32 + tl * 16 + lr;
#pragma unroll
      for (int rr = 0; rr < 4; ++rr) {
        int o2 = og * 48 + im * 16 + quad * 4 + rr;
        out[obase + (size_t)o2 * 16384 + pxx] = acc2[im][tl][rr] + b2e[o2];
      }
    }
  }
}

// ---------------------------------------------------------------------------
extern "C" void kernel_launch(void* const* d_in, const int* in_sizes, int n_in,
                              void* d_out, int out_size, void* d_ws, size_t ws_size,
                              hipStream_t stream)
{
  const float* x   = (const float*)d_in[0];
  const float* g1  = (const float*)d_in[1];
  const float* be1 = (const float*)d_in[2];
  const float* mu1 = (const float*)d_in[3];
  const float* va1 = (const float*)d_in[4];
  const float* W1  = (const float*)d_in[5];
  const float* cb1 = (const float*)d_in[6];
  const float* g2  = (const float*)d_in[7];
  const float* be2 = (const float*)d_in[8];
  const float* mu2 = (const float*)d_in[9];
  const float* va2 = (const float*)d_in[10];
  const float* W2  = (const float*)d_in[11];
  const float* cb2 = (const float*)d_in[12];
  float* out = (float*)d_out;

  hipFuncSetAttribute((const void*)fused1_kernel,
                      hipFuncAttributeMaxDynamicSharedMemorySize, 133120);

  char* w = (char*)d_ws;
  __hip_bfloat16* V   = (__hip_bfloat16*)w; w += (size_t)512 * 1248 * 2;
  __hip_bfloat16* W2e = (__hip_bfloat16*)w; w += (size_t)96 * 512 * 2;
  float* b1e = (float*)w; w += 2048;
  float* b2e = (float*)w; w += 512;
  size_t fixed = (size_t)(w - (char*)d_ws);

  const size_t satB = (size_t)96 * 17028 * 4;     // per-batch SAT bytes
  int nb = (ws_size >= fixed + 4 * satB + 4096) ? 4 : 1;

  float* SAT = (float*)w;

  prep1_kernel<<<512, 256, 0, stream>>>(W1, cb1, g1, be1, mu1, va1, V, b1e);
  prep2_kernel<<<96, 256, 0, stream>>>(W2, cb2, g2, be2, mu2, va2, W2e, b2e);

  for (int b0 = 0; b0 < 4; b0 += nb) {
    sat_kernel<<<nb * 96, 512, 0, stream>>>(x + (size_t)b0 * 96 * 16384, SAT);
    fused1_kernel<<<nb * 128, 512, 133120, stream>>>(SAT, V, b1e, W2e, b2e, out, nb, b0);
  }
}